// Round 10
// baseline (630.138 us; speedup 1.0000x reference)
//
#include <hip/hip_runtime.h>
#include <hip/hip_cooperative_groups.h>
#include <math.h>

namespace cg = cooperative_groups;

#define BB 2
#define LL 2048
#define DD 512
#define HH 8
#define DK 64
#define SK 40   // sample_k
#define UU 40   // top-k u
#define BH (BB*HH)   // 16
#define NBLK 512

typedef __attribute__((ext_vector_type(8))) __bf16 bf16x8;
typedef __attribute__((ext_vector_type(4))) float f32x4;

__device__ inline ushort f2bf_rn(float f) {
    unsigned u = __float_as_uint(f);
    unsigned r = (u + 0x7fffu + ((u >> 16) & 1u)) >> 16;
    return (ushort)r;
}
__device__ inline float bf2f(ushort h) { return __uint_as_float(((unsigned)h) << 16); }

__device__ __forceinline__ void gload16(const ushort* g, void* l) {
    __builtin_amdgcn_global_load_lds(
        (const __attribute__((address_space(1))) unsigned int*)g,
        (__attribute__((address_space(3))) unsigned int*)l,
        16, 0, 0);
}

// ===================== cooperative mega-kernel: 512 blocks x 256, 32KB smem arena =====================
__global__ __launch_bounds__(256, 2) void mega(
    const float* __restrict__ x,
    const float* __restrict__ Wq, const float* __restrict__ Wk, const float* __restrict__ Wv,
    const float* __restrict__ bq, const float* __restrict__ bk_, const float* __restrict__ bv,
    const int* __restrict__ idxs,
    float* __restrict__ q, float* __restrict__ k, float* __restrict__ v,
    float* __restrict__ M, float* __restrict__ sums,
    ushort* __restrict__ Ah, ushort* __restrict__ Al,
    ushort* __restrict__ Bh, ushort* __restrict__ Bl,
    float* __restrict__ ctx, float* __restrict__ attns,
    unsigned* __restrict__ fillctr)
{
    cg::grid_group grid = cg::this_grid();
    __shared__ __attribute__((aligned(16))) char smem[32768];
    const int tid = threadIdx.x;
    const int bid = blockIdx.x;

    // ================= P1: split-bf16 pack (grid-stride over 1408 virtual blocks) =================
    if (bid == 0 && tid == 0) *fillctr = 0u;
    for (int vb = bid; vb < 1408; vb += NBLK) {
        const float* src; ushort* dh; ushort* dl;
        if (vb < 1024) {
            const int g = vb * 256 + tid;
            const int r = g >> 6, c = (g & 63) * 8;
            src = x + (long)r * DD + c;
            dh = Ah + (long)r * DD + c;
            dl = Al + (long)r * DD + c;
        } else {
            const int wb = vb - 1024;
            const int p = wb >> 7;
            const float* W = (p == 0) ? Wq : ((p == 1) ? Wk : Wv);
            const int rem = (wb & 127) * 256 + tid;
            const int r = rem >> 6, c = (rem & 63) * 8;
            src = W + (long)r * DD + c;
            dh = Bh + ((long)p * DD + r) * DD + c;
            dl = Bl + ((long)p * DD + r) * DD + c;
        }
        const float4 f0 = *(const float4*)&src[0];
        const float4 f1 = *(const float4*)&src[4];
        float f[8] = {f0.x, f0.y, f0.z, f0.w, f1.x, f1.y, f1.z, f1.w};
        union { ushort s[8]; uint4 u; } H, L;
        #pragma unroll
        for (int i = 0; i < 8; ++i) {
            H.s[i] = f2bf_rn(f[i]);
            L.s[i] = f2bf_rn(f[i] - bf2f(H.s[i]));
        }
        *(uint4*)dh = H.u;
        *(uint4*)dl = L.u;
    }
    grid.sync();

    // ================= P2: MFMA proj (0..383) then all blocks steal fill chunks =================
    if (bid < 384) {
        const int pz = bid >> 7;
        const int rem = bid & 127;
        const int o0 = (rem >> 5) * 128;
        const int m0 = (rem & 31) * 128;
        const float* bias = (pz == 0) ? bq : ((pz == 1) ? bk_ : bv);
        float* out = (pz == 0) ? q : ((pz == 1) ? k : v);

        const ushort* Bp = Bh + (long)pz * DD * DD;
        const ushort* Blp = Bl + (long)pz * DD * DD;
        const ushort* segA[3] = {Ah, Ah, Al};
        const ushort* segB[3] = {Bp, Blp, Bp};

        ushort* As = (ushort*)smem;
        ushort* Bs = (ushort*)(smem + 16384);

        const int lane = tid & 63, w = tid >> 6;
        const int wr = w >> 1, wc = w & 1;
        const int ln15 = lane & 15;
        const int l3 = lane >> 3, l7 = (lane & 7) * 8;

        f32x4 acc[4][4] = {};

        for (int t = 0; t < 24; ++t) {
            const ushort* Aseg = segA[t >> 3];
            const ushort* Bseg = segB[t >> 3];
            const int k0 = (t & 7) * 64;
            __syncthreads();
            #pragma unroll
            for (int c = 0; c < 8; ++c) {
                const int j = w * 8 + c;
                if (j < 16) {
                    gload16(Aseg + (long)(m0 + j * 8 + l3) * DD + k0 + l7,
                            (char*)As + j * 1024);
                } else {
                    const int j2 = j - 16;
                    gload16(Bseg + (long)(o0 + j2 * 8 + l3) * DD + k0 + l7,
                            (char*)Bs + j2 * 1024);
                }
            }
            __syncthreads();
            #pragma unroll
            for (int ks = 0; ks < 2; ++ks) {
                const int kb = ks * 64 + (lane >> 4) * 16;
                bf16x8 bfr[4];
                #pragma unroll
                for (int jj = 0; jj < 4; ++jj)
                    bfr[jj] = *(const bf16x8*)((const char*)Bs + (wc * 64 + jj * 16 + ln15) * 128 + kb);
                #pragma unroll
                for (int i = 0; i < 4; ++i) {
                    bf16x8 af = *(const bf16x8*)((const char*)As + (wr * 64 + i * 16 + ln15) * 128 + kb);
                    #pragma unroll
                    for (int jj = 0; jj < 4; ++jj)
                        acc[i][jj] = __builtin_amdgcn_mfma_f32_16x16x32_bf16(af, bfr[jj], acc[i][jj], 0, 0, 0);
                }
            }
        }

        const int n_base = o0 + wc * 64;
        float bb[4];
        #pragma unroll
        for (int jj = 0; jj < 4; ++jj) bb[jj] = bias[n_base + jj * 16 + ln15];
        #pragma unroll
        for (int i = 0; i < 4; ++i) {
            #pragma unroll
            for (int jj = 0; jj < 4; ++jj) {
                const int n = n_base + jj * 16 + ln15;
                #pragma unroll
                for (int r = 0; r < 4; ++r) {
                    const int m = m0 + wr * 64 + i * 16 + (lane >> 4) * 4 + r;
                    out[(((long)(m >> 11) * HH + (n >> 6)) * LL + (m & (LL - 1))) * DK + (n & 63)] =
                        acc[i][jj][r] + bb[jj];
                }
            }
        }
    }
    // ---- fill attns via work-stealing (all 512 blocks; proj blocks join when done) ----
    {
        volatile int* chunk_s = (volatile int*)smem;
        const float c = 1.0f / (float)LL;
        const float4 val = make_float4(c, c, c, c);
        for (;;) {
            __syncthreads();                       // guard smem reuse + prior iteration
            if (tid == 0) *chunk_s = (int)atomicAdd(fillctr, 1u);
            __syncthreads();
            const int vb = *chunk_s;
            if (vb >= 2048) break;
            float4* p = (float4*)attns + (long)vb * 8192 + tid;
            #pragma unroll
            for (int i = 0; i < 32; ++i) p[i * 256] = val;
        }
    }
    grid.sync();

    // ================= P3: qk 4-way sample-split (all 512) || cumsum_p1 (blocks 0..255 append) =================
    {
        const int g = bid * 64 + (tid >> 2);
        const int part = tid & 3;
        const int bh = g >> 11, l = g & (LL - 1);
        const float* qr = q + ((long)bh * LL + l) * DK;
        float4 qv[16];
        #pragma unroll
        for (int i = 0; i < 16; ++i) qv[i] = *(const float4*)&qr[i * 4];

        const int* ir = idxs + (long)l * SK + part * 10;
        const float* kb = k + (long)bh * LL * DK;
        float mx = -INFINITY, sm = 0.f;
        #pragma unroll
        for (int s = 0; s < 10; ++s) {
            const float* kr = kb + (long)ir[s] * DK;
            float acc = 0.f;
            #pragma unroll
            for (int i = 0; i < 16; ++i) {
                float4 kv = *(const float4*)&kr[i * 4];
                acc += qv[i].x * kv.x + qv[i].y * kv.y + qv[i].z * kv.z + qv[i].w * kv.w;
            }
            mx = fmaxf(mx, acc); sm += acc;
        }
        mx = fmaxf(mx, __shfl_xor(mx, 1, 64));
        mx = fmaxf(mx, __shfl_xor(mx, 2, 64));
        sm += __shfl_xor(sm, 1, 64);
        sm += __shfl_xor(sm, 2, 64);
        if (part == 0) M[(long)bh * LL + l] = mx - sm * (1.0f / (float)LL);
    }
    if (bid < 256) {
        const int bh = bid >> 4;
        const int d = tid & 63, sc_ = tid >> 6;
        const int chunk = (bid & 15) * 4 + sc_;
        const float* vb = v + ((long)bh * LL + chunk * 32) * DK + d;
        float s = 0.f;
        #pragma unroll
        for (int r = 0; r < 32; ++r) s += vb[r * DK];
        sums[((long)bh * 64 + chunk) * DK + d] = s;
    }
    grid.sync();

    // ================= P4: topk + {scores (0..127) | cum-emit (128..383) | idle (384+)} =================
    if (bid >= 384) return;

    const bool isCum = bid >= 128;
    const int bh = isCum ? ((bid - 128) >> 4) : (bid >> 3);

    int* list = (int*)smem;                                   // 160 B
    unsigned* bmap = (unsigned*)(smem + 256);                 // 256 B

    if (tid < 64) bmap[tid] = 0u;
    __syncthreads();
    if (tid < 64) {
        const int lane = tid;
        float vals[32];
        #pragma unroll
        for (int r = 0; r < 32; ++r) vals[r] = M[(long)bh * LL + r * 64 + lane];
        for (int it = 0; it < UU; ++it) {
            float lm = vals[0];
            #pragma unroll
            for (int r = 1; r < 32; ++r) lm = fmaxf(lm, vals[r]);
            float wm = lm;
            #pragma unroll
            for (int s = 1; s < 64; s <<= 1) wm = fmaxf(wm, __shfl_xor(wm, s, 64));
            unsigned long long mask = __ballot(lm == wm);
            int first = (int)__ffsll(mask) - 1;
            if (lane == first) {
                #pragma unroll
                for (int r = 0; r < 32; ++r) {
                    if (vals[r] == wm) { list[it] = r * 64 + lane; vals[r] = -INFINITY; break; }
                }
            }
        }
    }
    __syncthreads();
    if (tid < UU) atomicOr(&bmap[list[tid] >> 5], 1u << (list[tid] & 31));
    __syncthreads();

    if (isCum) {
        const int b = bid - 128;
        const int d = tid & 63, sc_ = tid >> 6;
        const int chunk = (b & 15) * 4 + sc_;
        float carry = 0.f;
        for (int c = 0; c < chunk; ++c) carry += sums[((long)bh * 64 + c) * DK + d];
        const float* vb = v + ((long)bh * LL + chunk * 32) * DK + d;
        float* cb = ctx + ((long)bh * LL + chunk * 32) * DK + d;
        float run = carry;
        #pragma unroll
        for (int r = 0; r < 32; ++r) {
            run += vb[r * DK];
            const int l = chunk * 32 + r;
            if (!((bmap[l >> 5] >> (l & 31)) & 1u)) cb[r * DK] = run;
        }
        return;
    }

    // ---- scores role: 5 selected rows; softmax on scattered ownership; P->bf16 LDS for upd ----
    const int g = bid & 7;
    const int lane = tid & 63, wave = tid >> 6;
    float (*qs)[DK]  = (float(*)[DK])(smem + 512);            // 1280 B
    float (*red)[4]  = (float(*)[4])(smem + 1792);            // 80 B
    float (*red2)[5][DK] = (float(*)[5][DK])(smem + 2048);    // 5 KB
    ushort* scbf = (ushort*)(smem + 7168);                    // 20 KB: [5][2048] bf16

    if (tid < 80) {
        int u = tid >> 4, c4 = (tid & 15) * 4;
        *(float4*)&qs[u][c4] = *(const float4*)&q[((long)bh * LL + list[g * 5 + u]) * DK + c4];
    }
    __syncthreads();

    const float* kb = k + (long)bh * LL * DK;
    float a[8][5] = {};
    #pragma unroll
    for (int c = 0; c < DK; c += 4) {
        float4 qv[5];
        #pragma unroll
        for (int u = 0; u < 5; ++u) qv[u] = *(const float4*)&qs[u][c];
        #pragma unroll
        for (int r = 0; r < 8; ++r) {
            float4 kv = *(const float4*)&kb[(long)(tid + r * 256) * DK + c];
            #pragma unroll
            for (int u = 0; u < 5; ++u)
                a[r][u] += qv[u].x * kv.x + qv[u].y * kv.y + qv[u].z * kv.z + qv[u].w * kv.w;
        }
    }
    const float scale = 0.125f;
    #pragma unroll
    for (int r = 0; r < 8; ++r)
        #pragma unroll
        for (int u = 0; u < 5; ++u)
            a[r][u] *= scale;

    float mloc[5];
    #pragma unroll
    for (int u = 0; u < 5; ++u) {
        float m = a[0][u];
        #pragma unroll
        for (int r = 1; r < 8; ++r) m = fmaxf(m, a[r][u]);
        #pragma unroll
        for (int s = 1; s < 64; s <<= 1) m = fmaxf(m, __shfl_xor(m, s, 64));
        if (lane == 0) red[u][wave] = m;
    }
    __syncthreads();
    #pragma unroll
    for (int u = 0; u < 5; ++u)
        mloc[u] = fmaxf(fmaxf(red[u][0], red[u][1]), fmaxf(red[u][2], red[u][3]));
    __syncthreads();
    #pragma unroll
    for (int u = 0; u < 5; ++u) {
        float s = 0.f;
        #pragma unroll
        for (int r = 0; r < 8; ++r) { a[r][u] = expf(a[r][u] - mloc[u]); s += a[r][u]; }
        #pragma unroll
        for (int st = 1; st < 64; st <<= 1) s += __shfl_xor(s, st, 64);
        if (lane == 0) red[u][wave] = s;
    }
    __syncthreads();
    #pragma unroll
    for (int u = 0; u < 5; ++u) {
        const float inv = 1.0f / (red[u][0] + red[u][1] + red[u][2] + red[u][3]);
        float* row = attns + ((long)bh * LL + list[g * 5 + u]) * LL;
        #pragma unroll
        for (int r = 0; r < 8; ++r) {
            const float p = a[r][u] * inv;
            row[tid + r * 256] = p;                         // coalesced per r
            scbf[u * LL + tid + r * 256] = f2bf_rn(p);      // bf16 copy for upd
        }
    }
    __syncthreads();

    const int d = tid & 63, part = tid >> 6;
    const float* vb = v + (long)bh * LL * DK + d;
    float ua[5] = {};
    for (int l0 = part * 512; l0 < part * 512 + 512; l0 += 4) {
        float vv0 = vb[(long)(l0 + 0) * DK];
        float vv1 = vb[(long)(l0 + 1) * DK];
        float vv2 = vb[(long)(l0 + 2) * DK];
        float vv3 = vb[(long)(l0 + 3) * DK];
        #pragma unroll
        for (int u = 0; u < 5; ++u) {
            ushort4 pv = *(const ushort4*)&scbf[u * LL + l0];
            ua[u] += bf2f(pv.x) * vv0 + bf2f(pv.y) * vv1 + bf2f(pv.z) * vv2 + bf2f(pv.w) * vv3;
        }
    }
    #pragma unroll
    for (int u = 0; u < 5; ++u) red2[part][u][d] = ua[u];
    __syncthreads();
    if (part == 0) {
        #pragma unroll
        for (int u = 0; u < 5; ++u) {
            float s = red2[0][u][d] + red2[1][u][d] + red2[2][u][d] + red2[3][u][d];
            ctx[((long)bh * LL + list[g * 5 + u]) * DK + d] = s;
        }
    }
}

// ===================== fallback path: R8-verbatim 4-dispatch pipeline =====================
__global__ __launch_bounds__(256) void pack_split(
    const float* __restrict__ x,
    const float* __restrict__ Wq, const float* __restrict__ Wk, const float* __restrict__ Wv,
    ushort* __restrict__ Ah, ushort* __restrict__ Al,
    ushort* __restrict__ Bh, ushort* __restrict__ Bl)
{
    const int bid = blockIdx.x;
    const float* src; ushort* dh; ushort* dl;
    if (bid < 1024) {
        const int g = bid * 256 + threadIdx.x;
        const int r = g >> 6, c = (g & 63) * 8;
        src = x + (long)r * DD + c;
        dh = Ah + (long)r * DD + c;
        dl = Al + (long)r * DD + c;
    } else {
        const int wb = bid - 1024;
        const int p = wb >> 7;
        const float* W = (p == 0) ? Wq : ((p == 1) ? Wk : Wv);
        const int rem = (wb & 127) * 256 + threadIdx.x;
        const int r = rem >> 6, c = (rem & 63) * 8;
        src = W + (long)r * DD + c;
        dh = Bh + ((long)p * DD + r) * DD + c;
        dl = Bl + ((long)p * DD + r) * DD + c;
    }
    const float4 f0 = *(const float4*)&src[0];
    const float4 f1 = *(const float4*)&src[4];
    float f[8] = {f0.x, f0.y, f0.z, f0.w, f1.x, f1.y, f1.z, f1.w};
    union { ushort s[8]; uint4 u; } H, L;
    #pragma unroll
    for (int i = 0; i < 8; ++i) {
        H.s[i] = f2bf_rn(f[i]);
        L.s[i] = f2bf_rn(f[i] - bf2f(H.s[i]));
    }
    *(uint4*)dh = H.u;
    *(uint4*)dl = L.u;
}

__global__ __launch_bounds__(256) void k1_proj_fill(
    const ushort* __restrict__ Ah, const ushort* __restrict__ Al,
    const ushort* __restrict__ Bh, const ushort* __restrict__ Bl,
    const float* __restrict__ bq, const float* __restrict__ bk_, const float* __restrict__ bv,
    float* __restrict__ q, float* __restrict__ k, float* __restrict__ v,
    float* __restrict__ attns)
{
    const int tid = threadIdx.x;

    if (blockIdx.x >= 384) {
        const float c = 1.0f / (float)LL;
        const float4 val = make_float4(c, c, c, c);
        float4* p = (float4*)attns + (long)(blockIdx.x - 384) * 8192 + tid;
        #pragma unroll
        for (int i = 0; i < 32; ++i) p[i * 256] = val;
        return;
    }

    const int pz = blockIdx.x >> 7;
    const int rem = blockIdx.x & 127;
    const int o0 = (rem >> 5) * 128;
    const int m0 = (rem & 31) * 128;
    const float* bias = (pz == 0) ? bq : ((pz == 1) ? bk_ : bv);
    float* out = (pz == 0) ? q : ((pz == 1) ? k : v);

    const ushort* Bp = Bh + (long)pz * DD * DD;
    const ushort* Blp = Bl + (long)pz * DD * DD;
    const ushort* segA[3] = {Ah, Ah, Al};
    const ushort* segB[3] = {Bp, Blp, Bp};

    __shared__ __attribute__((aligned(16))) ushort As[128 * 64];
    __shared__ __attribute__((aligned(16))) ushort Bs[128 * 64];

    const int lane = tid & 63, w = tid >> 6;
    const int wr = w >> 1, wc = w & 1;
    const int ln15 = lane & 15;
    const int l3 = lane >> 3, l7 = (lane & 7) * 8;

    f32x4 acc[4][4] = {};

    for (int t = 0; t < 24; ++t) {
        const ushort* Aseg = segA[t >> 3];
        const ushort* Bseg = segB[t >> 3];
        const int k0 = (t & 7) * 64;
        __syncthreads();
        #pragma unroll
        for (int c = 0; c < 8; ++c) {
            const int j = w * 8 + c;
            if (j < 16) {
                gload16(Aseg + (long)(m0 + j * 8 + l3) * DD + k0 + l7,
                        (char*)As + j * 1024);
            } else {
                const int j2 = j - 16;
                gload16(Bseg + (long)(o0 + j2 * 8 + l3) * DD + k0 + l7,
                        (char*)Bs + j2 * 1024);
            }
        }
        __syncthreads();
        #pragma unroll
        for (int ks = 0; ks < 2; ++ks) {
            const int kb = ks * 64 + (lane >> 4) * 16;
            bf16x8 bfr[4];
            #pragma unroll
            for (int jj = 0; jj < 4; ++jj)
                bfr[jj] = *(const bf16x8*)((const char*)Bs + (wc * 64 + jj * 16 + ln15) * 128 + kb);
            #pragma unroll
            for (int i = 0; i < 4; ++i) {
                bf16x8 af = *(const bf16x8*)((const char*)As + (wr * 64 + i * 16 + ln15) * 128 + kb);
                #pragma unroll
                for (int jj = 0; jj < 4; ++jj)
                    acc[i][jj] = __builtin_amdgcn_mfma_f32_16x16x32_bf16(af, bfr[jj], acc[i][jj], 0, 0, 0);
            }
        }
    }

    const int n_base = o0 + wc * 64;
    float bb[4];
    #pragma unroll
    for (int jj = 0; jj < 4; ++jj) bb[jj] = bias[n_base + jj * 16 + ln15];
    #pragma unroll
    for (int i = 0; i < 4; ++i) {
        #pragma unroll
        for (int jj = 0; jj < 4; ++jj) {
            const int n = n_base + jj * 16 + ln15;
            #pragma unroll
            for (int r = 0; r < 4; ++r) {
                const int m = m0 + wr * 64 + i * 16 + (lane >> 4) * 4 + r;
                out[(((long)(m >> 11) * HH + (n >> 6)) * LL + (m & (LL - 1))) * DK + (n & 63)] =
                    acc[i][jj][r] + bb[jj];
            }
        }
    }
}

__global__ __launch_bounds__(256) void k2_qk_cumsum1(
    const float* __restrict__ q, const float* __restrict__ k, const float* __restrict__ v,
    const int* __restrict__ idxs, float* __restrict__ M, float* __restrict__ sums)
{
    const int tid = threadIdx.x;

    if (blockIdx.x >= 512) {
        const int b = blockIdx.x - 512;
        const int bh = b >> 4;
        const int d = tid & 63, sc_ = tid >> 6;
        const int chunk = (b & 15) * 4 + sc_;
        const float* vb = v + ((long)bh * LL + chunk * 32) * DK + d;
        float s = 0.f;
        #pragma unroll
        for (int r = 0; r < 32; ++r) s += vb[r * DK];
        sums[((long)bh * 64 + chunk) * DK + d] = s;
        return;
    }

    const int g = blockIdx.x * 64 + (tid >> 2);
    const int part = tid & 3;
    const int bh = g >> 11, l = g & (LL - 1);
    const float* qr = q + ((long)bh * LL + l) * DK;
    float4 qv[16];
    #pragma unroll
    for (int i = 0; i < 16; ++i) qv[i] = *(const float4*)&qr[i * 4];

    const int* ir = idxs + (long)l * SK + part * 10;
    const float* kb = k + (long)bh * LL * DK;
    float mx = -INFINITY, sm = 0.f;
    #pragma unroll
    for (int s = 0; s < 10; ++s) {
        const float* kr = kb + (long)ir[s] * DK;
        float acc = 0.f;
        #pragma unroll
        for (int i = 0; i < 16; ++i) {
            float4 kv = *(const float4*)&kr[i * 4];
            acc += qv[i].x * kv.x + qv[i].y * kv.y + qv[i].z * kv.z + qv[i].w * kv.w;
        }
        mx = fmaxf(mx, acc); sm += acc;
    }
    mx = fmaxf(mx, __shfl_xor(mx, 1, 64));
    mx = fmaxf(mx, __shfl_xor(mx, 2, 64));
    sm += __shfl_xor(sm, 1, 64);
    sm += __shfl_xor(sm, 2, 64);
    if (part == 0) M[(long)bh * LL + l] = mx - sm * (1.0f / (float)LL);
}

__global__ __launch_bounds__(256) void k4_all(
    const float* __restrict__ q, const float* __restrict__ k, const float* __restrict__ v,
    const float* __restrict__ M, const float* __restrict__ sums,
    float* __restrict__ attns, float* __restrict__ ctx)
{
    const int tid = threadIdx.x;
    const bool isCum = blockIdx.x >= 128;
    const int bh = isCum ? ((blockIdx.x - 128) >> 4) : (blockIdx.x >> 3);

    __shared__ int list[UU];
    __shared__ unsigned bmap[64];

    if (tid < 64) bmap[tid] = 0u;
    __syncthreads();
    if (tid < 64) {
        const int lane = tid;
        float vals[32];
        #pragma unroll
        for (int r = 0; r < 32; ++r) vals[r] = M[(long)bh * LL + r * 64 + lane];
        for (int it = 0; it < UU; ++it) {
            float lm = vals[0];
            #pragma unroll
            for (int r = 1; r < 32; ++r) lm = fmaxf(lm, vals[r]);
            float wm = lm;
            #pragma unroll
            for (int s = 1; s < 64; s <<= 1) wm = fmaxf(wm, __shfl_xor(wm, s, 64));
            unsigned long long mask = __ballot(lm == wm);
            int first = (int)__ffsll(mask) - 1;
            if (lane == first) {
                #pragma unroll
                for (int r = 0; r < 32; ++r) {
                    if (vals[r] == wm) { list[it] = r * 64 + lane; vals[r] = -INFINITY; break; }
                }
            }
        }
    }
    __syncthreads();
    if (tid < UU) atomicOr(&bmap[list[tid] >> 5], 1u << (list[tid] & 31));
    __syncthreads();

    if (isCum) {
        const int b = blockIdx.x - 128;
        const int d = tid & 63, sc_ = tid >> 6;
        const int chunk = (b & 15) * 4 + sc_;
        float carry = 0.f;
        for (int c = 0; c < chunk; ++c) carry += sums[((long)bh * 64 + c) * DK + d];
        const float* vb = v + ((long)bh * LL + chunk * 32) * DK + d;
        float* cb = ctx + ((long)bh * LL + chunk * 32) * DK + d;
        float run = carry;
        #pragma unroll
        for (int r = 0; r < 32; ++r) {
            run += vb[r * DK];
            const int l = chunk * 32 + r;
            if (!((bmap[l >> 5] >> (l & 31)) & 1u)) cb[r * DK] = run;
        }
        return;
    }

    const int g = blockIdx.x & 7;
    const int lane = tid & 63, wave = tid >> 6;
    __shared__ float qs[5][DK];
    __shared__ float sc[5][LL];
    __shared__ float red[5][4];
    __shared__ float red2[4][5][DK];

    if (tid < 80) {
        int u = tid >> 4, c4 = (tid & 15) * 4;
        *(float4*)&qs[u][c4] = *(const float4*)&q[((long)bh * LL + list[g * 5 + u]) * DK + c4];
    }
    __syncthreads();

    const float* kb = k + (long)bh * LL * DK;
    float a[8][5] = {};
    #pragma unroll
    for (int c = 0; c < DK; c += 4) {
        float4 qv[5];
        #pragma unroll
        for (int u = 0; u < 5; ++u) qv[u] = *(const float4*)&qs[u][c];
        #pragma unroll
        for (int r = 0; r < 8; ++r) {
            float4 kv = *(const float4*)&kb[(long)(tid + r * 256) * DK + c];
            #pragma unroll
            for (int u = 0; u < 5; ++u)
                a[r][u] += qv[u].x * kv.x + qv[u].y * kv.y + qv[u].z * kv.z + qv[u].w * kv.w;
        }
    }
    const float scale = 0.125f;
    #pragma unroll
    for (int r = 0; r < 8; ++r)
        #pragma unroll
        for (int u = 0; u < 5; ++u)
            sc[u][tid + r * 256] = a[r][u] * scale;
    __syncthreads();

    float xv[5][8];
    #pragma unroll
    for (int u = 0; u < 5; ++u) {
        float4 t0 = *(const float4*)&sc[u][tid * 8];
        float4 t1 = *(const float4*)&sc[u][tid * 8 + 4];
        xv[u][0] = t0.x; xv[u][1] = t0.y; xv[u][2] = t0.z; xv[u][3] = t0.w;
        xv[u][4] = t1.x; xv[u][5] = t1.y; xv[u][6] = t1.z; xv[u][7] = t1.w;
    }
    float mloc[5];
    #pragma unroll
    for (int u = 0; u < 5; ++u) {
        float m = xv[u][0];
        #pragma unroll
        for (int i = 1; i < 8; ++i) m = fmaxf(m, xv[u][i]);
        #pragma unroll
        for (int s = 1; s < 64; s <<= 1) m = fmaxf(m, __shfl_xor(m, s, 64));
        if (lane == 0) red[u][wave] = m;
        mloc[u] = m;
    }
    __syncthreads();
    #pragma unroll
    for (int u = 0; u < 5; ++u)
        mloc[u] = fmaxf(fmaxf(red[u][0], red[u][1]), fmaxf(red[u][2], red[u][3]));
    __syncthreads();
    #pragma unroll
    for (int u = 0; u < 5; ++u) {
        float s = 0.f;
        #pragma unroll
        for (int i = 0; i < 8; ++i) { xv[u][i] = expf(xv[u][i] - mloc[u]); s += xv[u][i]; }
        #pragma unroll
        for (int st = 1; st < 64; st <<= 1) s += __shfl_xor(s, st, 64);
        if (lane == 0) red[u][wave] = s;
    }
    __syncthreads();
    #pragma unroll
    for (int u = 0; u < 5; ++u) {
        float inv = 1.0f / (red[u][0] + red[u][1] + red[u][2] + red[u][3]);
        float* row = attns + ((long)bh * LL + list[g * 5 + u]) * LL;
        float4 o0, o1;
        o0.x = xv[u][0] * inv; o0.y = xv[u][1] * inv; o0.z = xv[u][2] * inv; o0.w = xv[u][3] * inv;
        o1.x = xv[u][4] * inv; o1.y = xv[u][5] * inv; o1.z = xv[u][6] * inv; o1.w = xv[u][7] * inv;
        *(float4*)&row[tid * 8] = o0;
        *(float4*)&row[tid * 8 + 4] = o1;
        *(float4*)&sc[u][tid * 8] = o0;
        *(float4*)&sc[u][tid * 8 + 4] = o1;
    }
    __syncthreads();

    const int d = tid & 63, part = tid >> 6;
    const float* vb = v + (long)bh * LL * DK + d;
    float ua[5] = {};
    for (int l0 = part * 512; l0 < part * 512 + 512; l0 += 4) {
        float vv0 = vb[(long)(l0 + 0) * DK];
        float vv1 = vb[(long)(l0 + 1) * DK];
        float vv2 = vb[(long)(l0 + 2) * DK];
        float vv3 = vb[(long)(l0 + 3) * DK];
        #pragma unroll
        for (int u = 0; u < 5; ++u) {
            float4 pv = *(const float4*)&sc[u][l0];
            ua[u] += pv.x * vv0 + pv.y * vv1 + pv.z * vv2 + pv.w * vv3;
        }
    }
    #pragma unroll
    for (int u = 0; u < 5; ++u) red2[part][u][d] = ua[u];
    __syncthreads();
    if (part == 0) {
        #pragma unroll
        for (int u = 0; u < 5; ++u) {
            float s = red2[0][u][d] + red2[1][u][d] + red2[2][u][d] + red2[3][u][d];
            ctx[((long)bh * LL + list[g * 5 + u]) * DK + d] = s;
        }
    }
}

extern "C" void kernel_launch(void* const* d_in, const int* in_sizes, int n_in,
                              void* d_out, int out_size, void* d_ws, size_t ws_size,
                              hipStream_t stream) {
    const float* x  = (const float*)d_in[0];
    const float* Wq = (const float*)d_in[1];
    const float* bq = (const float*)d_in[2];
    const float* Wk = (const float*)d_in[3];
    const float* bk = (const float*)d_in[4];
    const float* Wv = (const float*)d_in[5];
    const float* bv = (const float*)d_in[6];
    const int* idxs = (const int*)d_in[7];

    float* ctx   = (float*)d_out;                            // B*H*L*DK (8 MB)
    float* attns = (float*)d_out + (long)BB * HH * LL * DK;  // B*H*L*L (268 MB)

    char* w = (char*)d_ws;
    float* q    = (float*)w; w += (size_t)BB * HH * LL * DK * 4;
    float* k    = (float*)w; w += (size_t)BB * HH * LL * DK * 4;
    float* v    = (float*)w; w += (size_t)BB * HH * LL * DK * 4;
    float* M    = (float*)w; w += (size_t)BB * HH * LL * 4;
    float* sums = (float*)w; w += (size_t)BH * 64 * DK * 4;
    ushort* Bh  = (ushort*)w; w += (size_t)3 * DD * DD * 2;
    ushort* Bl  = (ushort*)w; w += (size_t)3 * DD * DD * 2;
    unsigned* fillctr = (unsigned*)w; w += 256;

    // Ah/Al live in the ctx output region (consumed in P2, ctx written in P4)
    ushort* Ah = (ushort*)ctx;                  // 4 MB
    ushort* Al = Ah + (size_t)4096 * DD;        // 4 MB

    void* args[] = {
        (void*)&x, (void*)&Wq, (void*)&Wk, (void*)&Wv,
        (void*)&bq, (void*)&bk, (void*)&bv, (void*)&idxs,
        (void*)&q, (void*)&k, (void*)&v, (void*)&M, (void*)&sums,
        (void*)&Ah, (void*)&Al, (void*)&Bh, (void*)&Bl,
        (void*)&ctx, (void*)&attns, (void*)&fillctr
    };
    hipError_t err = hipLaunchCooperativeKernel((const void*)mega, dim3(NBLK), dim3(256),
                                                args, 0, stream);
    if (err != hipSuccess) {
        // fallback: proven R8 4-dispatch pipeline
        pack_split<<<1408, 256, 0, stream>>>(x, Wq, Wk, Wv, Ah, Al, Bh, Bl);
        k1_proj_fill<<<384 + 2048, 256, 0, stream>>>(Ah, Al, Bh, Bl, bq, bk, bv, q, k, v, attns);
        k2_qk_cumsum1<<<512 + 256, 256, 0, stream>>>(q, k, v, idxs, M, sums);
        k4_all<<<128 + 256, 256, 0, stream>>>(q, k, v, M, sums, attns, ctx);
    }
}

// Round 11
// 243.925 us; speedup vs baseline: 2.5833x; 2.5833x over previous
//
#include <hip/hip_runtime.h>
#include <math.h>

#define BB 2
#define LL 2048
#define DD 512
#define HH 8
#define DK 64
#define SK 40   // sample_k
#define UU 40   // top-k u
#define BH (BB*HH)   // 16

typedef __attribute__((ext_vector_type(8))) __bf16 bf16x8;
typedef __attribute__((ext_vector_type(4))) float f32x4;

__device__ inline ushort f2bf_rn(float f) {
    unsigned u = __float_as_uint(f);
    unsigned r = (u + 0x7fffu + ((u >> 16) & 1u)) >> 16;
    return (ushort)r;
}
__device__ inline float bf2f(ushort h) { return __uint_as_float(((unsigned)h) << 16); }

__device__ __forceinline__ void gload16(const ushort* g, void* l) {
    __builtin_amdgcn_global_load_lds(
        (const __attribute__((address_space(1))) unsigned int*)g,
        (__attribute__((address_space(3))) unsigned int*)l,
        16, 0, 0);
}

// =============== K0: pack x -> Ah/Al, W -> Bh/Bl (split-bf16) — R6/R8 verbatim ===============
__global__ __launch_bounds__(256) void pack_split(
    const float* __restrict__ x,
    const float* __restrict__ Wq, const float* __restrict__ Wk, const float* __restrict__ Wv,
    ushort* __restrict__ Ah, ushort* __restrict__ Al,
    ushort* __restrict__ Bh, ushort* __restrict__ Bl)
{
    const int bid = blockIdx.x;
    const float* src; ushort* dh; ushort* dl;
    if (bid < 1024) {
        const int g = bid * 256 + threadIdx.x;
        const int r = g >> 6, c = (g & 63) * 8;
        src = x + (long)r * DD + c;
        dh = Ah + (long)r * DD + c;
        dl = Al + (long)r * DD + c;
    } else {
        const int wb = bid - 1024;
        const int p = wb >> 7;
        const float* W = (p == 0) ? Wq : ((p == 1) ? Wk : Wv);
        const int rem = (wb & 127) * 256 + threadIdx.x;
        const int r = rem >> 6, c = (rem & 63) * 8;
        src = W + (long)r * DD + c;
        dh = Bh + ((long)p * DD + r) * DD + c;
        dl = Bl + ((long)p * DD + r) * DD + c;
    }
    const float4 f0 = *(const float4*)&src[0];
    const float4 f1 = *(const float4*)&src[4];
    float f[8] = {f0.x, f0.y, f0.z, f0.w, f1.x, f1.y, f1.z, f1.w};
    union { ushort s[8]; uint4 u; } H, L;
    #pragma unroll
    for (int i = 0; i < 8; ++i) {
        H.s[i] = f2bf_rn(f[i]);
        L.s[i] = f2bf_rn(f[i] - bf2f(H.s[i]));
    }
    *(uint4*)dh = H.u;
    *(uint4*)dl = L.u;
}

// =============== K1: MFMA proj (blocks 0..383) || fill attns (384..2431) — R6/R8 verbatim ===============
__global__ __launch_bounds__(256) void k1_proj_fill(
    const ushort* __restrict__ Ah, const ushort* __restrict__ Al,
    const ushort* __restrict__ Bh, const ushort* __restrict__ Bl,
    const float* __restrict__ bq, const float* __restrict__ bk_, const float* __restrict__ bv,
    float* __restrict__ q, float* __restrict__ k, float* __restrict__ v,
    float* __restrict__ attns)
{
    const int tid = threadIdx.x;

    if (blockIdx.x >= 384) {
        const float c = 1.0f / (float)LL;
        const float4 val = make_float4(c, c, c, c);
        float4* p = (float4*)attns + (long)(blockIdx.x - 384) * 8192 + tid;
        #pragma unroll
        for (int i = 0; i < 32; ++i) p[i * 256] = val;
        return;
    }

    const int pz = blockIdx.x >> 7;
    const int rem = blockIdx.x & 127;
    const int o0 = (rem >> 5) * 128;
    const int m0 = (rem & 31) * 128;
    const float* bias = (pz == 0) ? bq : ((pz == 1) ? bk_ : bv);
    float* out = (pz == 0) ? q : ((pz == 1) ? k : v);

    const ushort* Bp = Bh + (long)pz * DD * DD;
    const ushort* Blp = Bl + (long)pz * DD * DD;
    const ushort* segA[3] = {Ah, Ah, Al};
    const ushort* segB[3] = {Bp, Blp, Bp};

    __shared__ __attribute__((aligned(16))) ushort As[128 * 64];
    __shared__ __attribute__((aligned(16))) ushort Bs[128 * 64];

    const int lane = tid & 63, w = tid >> 6;
    const int wr = w >> 1, wc = w & 1;
    const int ln15 = lane & 15;
    const int l3 = lane >> 3, l7 = (lane & 7) * 8;

    f32x4 acc[4][4] = {};

    for (int t = 0; t < 24; ++t) {
        const ushort* Aseg = segA[t >> 3];
        const ushort* Bseg = segB[t >> 3];
        const int k0 = (t & 7) * 64;
        __syncthreads();
        #pragma unroll
        for (int c = 0; c < 8; ++c) {
            const int j = w * 8 + c;
            if (j < 16) {
                gload16(Aseg + (long)(m0 + j * 8 + l3) * DD + k0 + l7,
                        (char*)As + j * 1024);
            } else {
                const int j2 = j - 16;
                gload16(Bseg + (long)(o0 + j2 * 8 + l3) * DD + k0 + l7,
                        (char*)Bs + j2 * 1024);
            }
        }
        __syncthreads();
        #pragma unroll
        for (int ks = 0; ks < 2; ++ks) {
            const int kb = ks * 64 + (lane >> 4) * 16;
            bf16x8 bfr[4];
            #pragma unroll
            for (int jj = 0; jj < 4; ++jj)
                bfr[jj] = *(const bf16x8*)((const char*)Bs + (wc * 64 + jj * 16 + ln15) * 128 + kb);
            #pragma unroll
            for (int i = 0; i < 4; ++i) {
                bf16x8 af = *(const bf16x8*)((const char*)As + (wr * 64 + i * 16 + ln15) * 128 + kb);
                #pragma unroll
                for (int jj = 0; jj < 4; ++jj)
                    acc[i][jj] = __builtin_amdgcn_mfma_f32_16x16x32_bf16(af, bfr[jj], acc[i][jj], 0, 0, 0);
            }
        }
    }

    const int n_base = o0 + wc * 64;
    float bb[4];
    #pragma unroll
    for (int jj = 0; jj < 4; ++jj) bb[jj] = bias[n_base + jj * 16 + ln15];
    #pragma unroll
    for (int i = 0; i < 4; ++i) {
        #pragma unroll
        for (int jj = 0; jj < 4; ++jj) {
            const int n = n_base + jj * 16 + ln15;
            #pragma unroll
            for (int r = 0; r < 4; ++r) {
                const int m = m0 + wr * 64 + i * 16 + (lane >> 4) * 4 + r;
                out[(((long)(m >> 11) * HH + (n >> 6)) * LL + (m & (LL - 1))) * DK + (n & 63)] =
                    acc[i][jj][r] + bb[jj];
            }
        }
    }
}

// =============== K2: qk_sample 8-way s-split (blocks 0..1023) || cumsum_p1 (1024..1279) ===============
__global__ __launch_bounds__(256) void k2_qk_cumsum1(
    const float* __restrict__ q, const float* __restrict__ k, const float* __restrict__ v,
    const int* __restrict__ idxs, float* __restrict__ M, float* __restrict__ sums)
{
    const int tid = threadIdx.x;

    if (blockIdx.x >= 1024) {
        const int b = blockIdx.x - 1024;
        const int bh = b >> 4;
        const int d = tid & 63, sc_ = tid >> 6;
        const int chunk = (b & 15) * 4 + sc_;
        const float* vb = v + ((long)bh * LL + chunk * 32) * DK + d;
        float s = 0.f;
        #pragma unroll
        for (int r = 0; r < 32; ++r) s += vb[r * DK];
        sums[((long)bh * 64 + chunk) * DK + d] = s;
        return;
    }

    // 8 lanes per query: lane part handles samples part*5 .. +4
    const int g = blockIdx.x * 32 + (tid >> 3);      // query 0..32767
    const int part = tid & 7;
    const int bh = g >> 11, l = g & (LL - 1);
    const float* qr = q + ((long)bh * LL + l) * DK;
    float4 qv[16];
    #pragma unroll
    for (int i = 0; i < 16; ++i) qv[i] = *(const float4*)&qr[i * 4];

    const int* ir = idxs + (long)l * SK + part * 5;
    const float* kb = k + (long)bh * LL * DK;
    float mx = -INFINITY, sm = 0.f;
    #pragma unroll
    for (int s = 0; s < 5; ++s) {
        const float* kr = kb + (long)ir[s] * DK;
        float acc = 0.f;
        #pragma unroll
        for (int i = 0; i < 16; ++i) {
            float4 kv = *(const float4*)&kr[i * 4];
            acc += qv[i].x * kv.x + qv[i].y * kv.y + qv[i].z * kv.z + qv[i].w * kv.w;
        }
        mx = fmaxf(mx, acc); sm += acc;
    }
    mx = fmaxf(mx, __shfl_xor(mx, 1, 64));
    mx = fmaxf(mx, __shfl_xor(mx, 2, 64));
    mx = fmaxf(mx, __shfl_xor(mx, 4, 64));
    sm += __shfl_xor(sm, 1, 64);
    sm += __shfl_xor(sm, 2, 64);
    sm += __shfl_xor(sm, 4, 64);
    if (part == 0) M[(long)bh * LL + l] = mx - sm * (1.0f / (float)LL);
}

// =============== K4: topk-recompute + {scores 2 rows/block (0..319) | cum-emit (320..575)} ===============
__global__ __launch_bounds__(256) void k4_all(
    const float* __restrict__ q, const float* __restrict__ k, const float* __restrict__ v,
    const float* __restrict__ M, const float* __restrict__ sums,
    float* __restrict__ attns, float* __restrict__ ctx)
{
    const int tid = threadIdx.x;
    const bool isCum = blockIdx.x >= 320;
    const int bh = isCum ? ((blockIdx.x - 320) >> 4) : (blockIdx.x / 20);

    __shared__ int list[UU];
    __shared__ unsigned bmap[64];

    if (tid < 64) bmap[tid] = 0u;
    __syncthreads();
    if (tid < 64) {
        // wave-0 deterministic top-40 recompute (identical code+input across blocks)
        const int lane = tid;
        float vals[32];
        #pragma unroll
        for (int r = 0; r < 32; ++r) vals[r] = M[(long)bh * LL + r * 64 + lane];
        for (int it = 0; it < UU; ++it) {
            float lm = vals[0];
            #pragma unroll
            for (int r = 1; r < 32; ++r) lm = fmaxf(lm, vals[r]);
            float wm = lm;
            #pragma unroll
            for (int s = 1; s < 64; s <<= 1) wm = fmaxf(wm, __shfl_xor(wm, s, 64));
            unsigned long long mask = __ballot(lm == wm);
            int first = (int)__ffsll(mask) - 1;
            if (lane == first) {
                #pragma unroll
                for (int r = 0; r < 32; ++r) {
                    if (vals[r] == wm) { list[it] = r * 64 + lane; vals[r] = -INFINITY; break; }
                }
            }
        }
    }
    __syncthreads();
    if (tid < UU) atomicOr(&bmap[list[tid] >> 5], 1u << (list[tid] & 31));
    __syncthreads();

    if (isCum) {
        // ---- cumsum emit, skipping selected rows (scatter owns them) ----
        const int b = blockIdx.x - 320;
        const int d = tid & 63, sc_ = tid >> 6;
        const int chunk = (b & 15) * 4 + sc_;
        float carry = 0.f;
        for (int c = 0; c < chunk; ++c) carry += sums[((long)bh * 64 + c) * DK + d];
        const float* vb = v + ((long)bh * LL + chunk * 32) * DK + d;
        float* cb = ctx + ((long)bh * LL + chunk * 32) * DK + d;
        float run = carry;
        #pragma unroll
        for (int r = 0; r < 32; ++r) {
            run += vb[r * DK];
            const int l = chunk * 32 + r;
            if (!((bmap[l >> 5] >> (l & 31)) & 1u)) cb[r * DK] = run;
        }
        return;
    }

    // ---- scores role: 2 selected rows per block ----
    const int g2 = blockIdx.x % 20;                // row pair 0..19
    const int lane = tid & 63, wave = tid >> 6;
    __shared__ float qs[2][DK];
    __shared__ float sc[2][LL];                    // 16 KB
    __shared__ float red[2][4];
    __shared__ float red2[4][2][DK];               // 2 KB

    if (tid < 32) {
        int u = tid >> 4, c4 = (tid & 15) * 4;
        *(float4*)&qs[u][c4] = *(const float4*)&q[((long)bh * LL + list[g2 * 2 + u]) * DK + c4];
    }
    __syncthreads();

    const float* kb = k + (long)bh * LL * DK;
    float a[8][2] = {};
    #pragma unroll
    for (int c = 0; c < DK; c += 4) {
        float4 qv[2];
        #pragma unroll
        for (int u = 0; u < 2; ++u) qv[u] = *(const float4*)&qs[u][c];
        #pragma unroll
        for (int r = 0; r < 8; ++r) {
            float4 kv = *(const float4*)&kb[(long)(tid + r * 256) * DK + c];
            #pragma unroll
            for (int u = 0; u < 2; ++u)
                a[r][u] += qv[u].x * kv.x + qv[u].y * kv.y + qv[u].z * kv.z + qv[u].w * kv.w;
        }
    }
    const float scale = 0.125f;
    #pragma unroll
    for (int r = 0; r < 8; ++r)
        #pragma unroll
        for (int u = 0; u < 2; ++u)
            sc[u][tid + r * 256] = a[r][u] * scale;
    __syncthreads();

    float xv[2][8];
    #pragma unroll
    for (int u = 0; u < 2; ++u) {
        float4 t0 = *(const float4*)&sc[u][tid * 8];
        float4 t1 = *(const float4*)&sc[u][tid * 8 + 4];
        xv[u][0] = t0.x; xv[u][1] = t0.y; xv[u][2] = t0.z; xv[u][3] = t0.w;
        xv[u][4] = t1.x; xv[u][5] = t1.y; xv[u][6] = t1.z; xv[u][7] = t1.w;
    }
    float mloc[2];
    #pragma unroll
    for (int u = 0; u < 2; ++u) {
        float m = xv[u][0];
        #pragma unroll
        for (int i = 1; i < 8; ++i) m = fmaxf(m, xv[u][i]);
        #pragma unroll
        for (int s = 1; s < 64; s <<= 1) m = fmaxf(m, __shfl_xor(m, s, 64));
        if (lane == 0) red[u][wave] = m;
        mloc[u] = m;
    }
    __syncthreads();
    #pragma unroll
    for (int u = 0; u < 2; ++u)
        mloc[u] = fmaxf(fmaxf(red[u][0], red[u][1]), fmaxf(red[u][2], red[u][3]));
    __syncthreads();
    #pragma unroll
    for (int u = 0; u < 2; ++u) {
        float s = 0.f;
        #pragma unroll
        for (int i = 0; i < 8; ++i) { xv[u][i] = expf(xv[u][i] - mloc[u]); s += xv[u][i]; }
        #pragma unroll
        for (int st = 1; st < 64; st <<= 1) s += __shfl_xor(s, st, 64);
        if (lane == 0) red[u][wave] = s;
    }
    __syncthreads();
    #pragma unroll
    for (int u = 0; u < 2; ++u) {
        float inv = 1.0f / (red[u][0] + red[u][1] + red[u][2] + red[u][3]);
        float* row = attns + ((long)bh * LL + list[g2 * 2 + u]) * LL;
        float4 o0, o1;
        o0.x = xv[u][0] * inv; o0.y = xv[u][1] * inv; o0.z = xv[u][2] * inv; o0.w = xv[u][3] * inv;
        o1.x = xv[u][4] * inv; o1.y = xv[u][5] * inv; o1.z = xv[u][6] * inv; o1.w = xv[u][7] * inv;
        *(float4*)&row[tid * 8] = o0;
        *(float4*)&row[tid * 8 + 4] = o1;
        *(float4*)&sc[u][tid * 8] = o0;       // normalized probs back to LDS for upd
        *(float4*)&sc[u][tid * 8 + 4] = o1;
    }
    __syncthreads();

    const int d = tid & 63, part = tid >> 6;
    const float* vb = v + (long)bh * LL * DK + d;
    float ua[2] = {};
    for (int l0 = part * 512; l0 < part * 512 + 512; l0 += 4) {
        float vv0 = vb[(long)(l0 + 0) * DK];
        float vv1 = vb[(long)(l0 + 1) * DK];
        float vv2 = vb[(long)(l0 + 2) * DK];
        float vv3 = vb[(long)(l0 + 3) * DK];
        #pragma unroll
        for (int u = 0; u < 2; ++u) {
            float4 pv = *(const float4*)&sc[u][l0];
            ua[u] += pv.x * vv0 + pv.y * vv1 + pv.z * vv2 + pv.w * vv3;
        }
    }
    #pragma unroll
    for (int u = 0; u < 2; ++u) red2[part][u][d] = ua[u];
    __syncthreads();
    if (part == 0) {
        #pragma unroll
        for (int u = 0; u < 2; ++u) {
            float s = red2[0][u][d] + red2[1][u][d] + red2[2][u][d] + red2[3][u][d];
            ctx[((long)bh * LL + list[g2 * 2 + u]) * DK + d] = s;
        }
    }
}

extern "C" void kernel_launch(void* const* d_in, const int* in_sizes, int n_in,
                              void* d_out, int out_size, void* d_ws, size_t ws_size,
                              hipStream_t stream) {
    const float* x  = (const float*)d_in[0];
    const float* Wq = (const float*)d_in[1];
    const float* bq = (const float*)d_in[2];
    const float* Wk = (const float*)d_in[3];
    const float* bk = (const float*)d_in[4];
    const float* Wv = (const float*)d_in[5];
    const float* bv = (const float*)d_in[6];
    const int* idxs = (const int*)d_in[7];

    float* ctx   = (float*)d_out;                            // B*H*L*DK (8 MB)
    float* attns = (float*)d_out + (long)BB * HH * LL * DK;  // B*H*L*L (268 MB)

    char* w = (char*)d_ws;
    float* q    = (float*)w; w += (size_t)BB * HH * LL * DK * 4;
    float* k    = (float*)w; w += (size_t)BB * HH * LL * DK * 4;
    float* v    = (float*)w; w += (size_t)BB * HH * LL * DK * 4;
    float* M    = (float*)w; w += (size_t)BB * HH * LL * 4;
    float* sums = (float*)w; w += (size_t)BH * 64 * DK * 4;
    ushort* Bh  = (ushort*)w; w += (size_t)3 * DD * DD * 2;
    ushort* Bl  = (ushort*)w; w += (size_t)3 * DD * DD * 2;

    // Ah/Al live in the ctx output region (consumed by K1; ctx written in K4)
    ushort* Ah = (ushort*)ctx;                  // 4 MB
    ushort* Al = Ah + (size_t)4096 * DD;        // 4 MB

    // K0: split-bf16 packing
    pack_split<<<1408, 256, 0, stream>>>(x, Wq, Wk, Wv, Ah, Al, Bh, Bl);

    // K1: MFMA projections (384 blocks) || fill attns (2048 blocks)
    k1_proj_fill<<<384 + 2048, 256, 0, stream>>>(Ah, Al, Bh, Bl, bq, bk, bv, q, k, v, attns);

    // K2: sampled QK^T 8-way split (1024) || cumsum chunk sums (256)
    k2_qk_cumsum1<<<1024 + 256, 256, 0, stream>>>(q, k, v, idxs, M, sums);

    // K4: topk-recompute + scores/softmax/upd/scatter 2 rows/block (320) || cumsum emit (256)
    k4_all<<<320 + 256, 256, 0, stream>>>(q, k, v, M, sums, attns, ctx);
}

// Round 12
// 197.058 us; speedup vs baseline: 3.1977x; 1.2378x over previous
//
#include <hip/hip_runtime.h>
#include <math.h>

#define BB 2
#define LL 2048
#define DD 512
#define HH 8
#define DK 64
#define SK 40   // sample_k
#define UU 40   // top-k u
#define BH (BB*HH)   // 16

typedef __attribute__((ext_vector_type(8))) __bf16 bf16x8;
typedef __attribute__((ext_vector_type(4))) float f32x4;

__device__ inline ushort f2bf_rn(float f) {
    unsigned u = __float_as_uint(f);
    unsigned r = (u + 0x7fffu + ((u >> 16) & 1u)) >> 16;
    return (ushort)r;
}
__device__ inline float bf2f(ushort h) { return __uint_as_float(((unsigned)h) << 16); }

__device__ __forceinline__ void gload16(const ushort* g, void* l) {
    __builtin_amdgcn_global_load_lds(
        (const __attribute__((address_space(1))) unsigned int*)g,
        (__attribute__((address_space(3))) unsigned int*)l,
        16, 0, 0);
}

// =============== K0: pack x -> Ah/Al, W -> Bh/Bl (split-bf16) — R8 verbatim ===============
__global__ __launch_bounds__(256) void pack_split(
    const float* __restrict__ x,
    const float* __restrict__ Wq, const float* __restrict__ Wk, const float* __restrict__ Wv,
    ushort* __restrict__ Ah, ushort* __restrict__ Al,
    ushort* __restrict__ Bh, ushort* __restrict__ Bl)
{
    const int bid = blockIdx.x;
    const float* src; ushort* dh; ushort* dl;
    if (bid < 1024) {
        const int g = bid * 256 + threadIdx.x;
        const int r = g >> 6, c = (g & 63) * 8;
        src = x + (long)r * DD + c;
        dh = Ah + (long)r * DD + c;
        dl = Al + (long)r * DD + c;
    } else {
        const int wb = bid - 1024;
        const int p = wb >> 7;
        const float* W = (p == 0) ? Wq : ((p == 1) ? Wk : Wv);
        const int rem = (wb & 127) * 256 + threadIdx.x;
        const int r = rem >> 6, c = (rem & 63) * 8;
        src = W + (long)r * DD + c;
        dh = Bh + ((long)p * DD + r) * DD + c;
        dl = Bl + ((long)p * DD + r) * DD + c;
    }
    const float4 f0 = *(const float4*)&src[0];
    const float4 f1 = *(const float4*)&src[4];
    float f[8] = {f0.x, f0.y, f0.z, f0.w, f1.x, f1.y, f1.z, f1.w};
    union { ushort s[8]; uint4 u; } H, L;
    #pragma unroll
    for (int i = 0; i < 8; ++i) {
        H.s[i] = f2bf_rn(f[i]);
        L.s[i] = f2bf_rn(f[i] - bf2f(H.s[i]));
    }
    *(uint4*)dh = H.u;
    *(uint4*)dl = L.u;
}

// =============== K1: MFMA proj (blocks 0..383) || fill attns (384..2431) — R8 verbatim ===============
__global__ __launch_bounds__(256) void k1_proj_fill(
    const ushort* __restrict__ Ah, const ushort* __restrict__ Al,
    const ushort* __restrict__ Bh, const ushort* __restrict__ Bl,
    const float* __restrict__ bq, const float* __restrict__ bk_, const float* __restrict__ bv,
    float* __restrict__ q, float* __restrict__ k, float* __restrict__ v,
    float* __restrict__ attns)
{
    const int tid = threadIdx.x;

    if (blockIdx.x >= 384) {
        const float c = 1.0f / (float)LL;
        const float4 val = make_float4(c, c, c, c);
        float4* p = (float4*)attns + (long)(blockIdx.x - 384) * 8192 + tid;
        #pragma unroll
        for (int i = 0; i < 32; ++i) p[i * 256] = val;
        return;
    }

    const int pz = blockIdx.x >> 7;
    const int rem = blockIdx.x & 127;
    const int o0 = (rem >> 5) * 128;
    const int m0 = (rem & 31) * 128;
    const float* bias = (pz == 0) ? bq : ((pz == 1) ? bk_ : bv);
    float* out = (pz == 0) ? q : ((pz == 1) ? k : v);

    const ushort* Bp = Bh + (long)pz * DD * DD;
    const ushort* Blp = Bl + (long)pz * DD * DD;
    const ushort* segA[3] = {Ah, Ah, Al};
    const ushort* segB[3] = {Bp, Blp, Bp};

    __shared__ __attribute__((aligned(16))) ushort As[128 * 64];
    __shared__ __attribute__((aligned(16))) ushort Bs[128 * 64];

    const int lane = tid & 63, w = tid >> 6;
    const int wr = w >> 1, wc = w & 1;
    const int ln15 = lane & 15;
    const int l3 = lane >> 3, l7 = (lane & 7) * 8;

    f32x4 acc[4][4] = {};

    for (int t = 0; t < 24; ++t) {
        const ushort* Aseg = segA[t >> 3];
        const ushort* Bseg = segB[t >> 3];
        const int k0 = (t & 7) * 64;
        __syncthreads();
        #pragma unroll
        for (int c = 0; c < 8; ++c) {
            const int j = w * 8 + c;
            if (j < 16) {
                gload16(Aseg + (long)(m0 + j * 8 + l3) * DD + k0 + l7,
                        (char*)As + j * 1024);
            } else {
                const int j2 = j - 16;
                gload16(Bseg + (long)(o0 + j2 * 8 + l3) * DD + k0 + l7,
                        (char*)Bs + j2 * 1024);
            }
        }
        __syncthreads();
        #pragma unroll
        for (int ks = 0; ks < 2; ++ks) {
            const int kb = ks * 64 + (lane >> 4) * 16;
            bf16x8 bfr[4];
            #pragma unroll
            for (int jj = 0; jj < 4; ++jj)
                bfr[jj] = *(const bf16x8*)((const char*)Bs + (wc * 64 + jj * 16 + ln15) * 128 + kb);
            #pragma unroll
            for (int i = 0; i < 4; ++i) {
                bf16x8 af = *(const bf16x8*)((const char*)As + (wr * 64 + i * 16 + ln15) * 128 + kb);
                #pragma unroll
                for (int jj = 0; jj < 4; ++jj)
                    acc[i][jj] = __builtin_amdgcn_mfma_f32_16x16x32_bf16(af, bfr[jj], acc[i][jj], 0, 0, 0);
            }
        }
    }

    const int n_base = o0 + wc * 64;
    float bb[4];
    #pragma unroll
    for (int jj = 0; jj < 4; ++jj) bb[jj] = bias[n_base + jj * 16 + ln15];
    #pragma unroll
    for (int i = 0; i < 4; ++i) {
        #pragma unroll
        for (int jj = 0; jj < 4; ++jj) {
            const int n = n_base + jj * 16 + ln15;
            #pragma unroll
            for (int r = 0; r < 4; ++r) {
                const int m = m0 + wr * 64 + i * 16 + (lane >> 4) * 4 + r;
                out[(((long)(m >> 11) * HH + (n >> 6)) * LL + (m & (LL - 1))) * DK + (n & 63)] =
                    acc[i][jj][r] + bb[jj];
            }
        }
    }
}

// =============== K2: qk_sample 4-way (blocks 0..511, XCD-swizzled) || cumsum_p1 (512..767, swizzled) ===============
// bh -> XCD residue (bh & 7): every block of bh lands at bid % 8 == bh % 8, so each XCD's L2
// caches exactly 2 bh k-slices (4 MB) for the 39x-reuse gather.
__global__ __launch_bounds__(256) void k2_qk_cumsum1(
    const float* __restrict__ q, const float* __restrict__ k, const float* __restrict__ v,
    const int* __restrict__ idxs, float* __restrict__ M, float* __restrict__ sums)
{
    const int tid = threadIdx.x;

    if (blockIdx.x >= 512) {
        const int b = blockIdx.x - 512;          // 0..255, 16 per bh
        const int r8 = b & 7, t = b >> 3;        // t: 0..31
        const int bh = ((t >> 4) << 3) | r8;     // bh % 8 == bid % 8
        const int cgrp = t & 15;
        const int d = tid & 63, sc_ = tid >> 6;
        const int chunk = cgrp * 4 + sc_;
        const float* vb = v + ((long)bh * LL + chunk * 32) * DK + d;
        float s = 0.f;
        #pragma unroll
        for (int r = 0; r < 32; ++r) s += vb[r * DK];
        sums[((long)bh * 64 + chunk) * DK + d] = s;
        return;
    }

    // qk: 32 blocks per bh, swizzled so all land on XCD (bh & 7)
    const int r8 = blockIdx.x & 7, t = blockIdx.x >> 3;   // t: 0..63
    const int bh = ((t >> 5) << 3) | r8;
    const int j = t & 31;                                 // query chunk within bh
    const int l = j * 64 + (tid >> 2);
    const int part = tid & 3;
    const float* qr = q + ((long)bh * LL + l) * DK;
    float4 qv[16];
    #pragma unroll
    for (int i = 0; i < 16; ++i) qv[i] = *(const float4*)&qr[i * 4];

    const int* ir = idxs + (long)l * SK + part * 10;
    const float* kb = k + (long)bh * LL * DK;
    float mx = -INFINITY, sm = 0.f;
    #pragma unroll
    for (int s = 0; s < 10; ++s) {
        const float* kr = kb + (long)ir[s] * DK;
        float acc = 0.f;
        #pragma unroll
        for (int i = 0; i < 16; ++i) {
            float4 kv = *(const float4*)&kr[i * 4];
            acc += qv[i].x * kv.x + qv[i].y * kv.y + qv[i].z * kv.z + qv[i].w * kv.w;
        }
        mx = fmaxf(mx, acc); sm += acc;
    }
    mx = fmaxf(mx, __shfl_xor(mx, 1, 64));
    mx = fmaxf(mx, __shfl_xor(mx, 2, 64));
    sm += __shfl_xor(sm, 1, 64);
    sm += __shfl_xor(sm, 2, 64);
    if (part == 0) M[(long)bh * LL + l] = mx - sm * (1.0f / (float)LL);
}

// =============== K4: topk-recompute + {scores 5 rows (0..127) | cum-emit (128..383)}, XCD-swizzled ===============
__global__ __launch_bounds__(256) void k4_all(
    const float* __restrict__ q, const float* __restrict__ k, const float* __restrict__ v,
    const float* __restrict__ M, const float* __restrict__ sums,
    float* __restrict__ attns, float* __restrict__ ctx)
{
    const int tid = threadIdx.x;
    const bool isCum = blockIdx.x >= 128;
    int bh, role;   // role: scores group g (0..7) or cum chunk-group (0..15)
    if (isCum) {
        const int b = blockIdx.x - 128;          // 0..255
        const int r8 = b & 7, t = b >> 3;        // t: 0..31
        bh = ((t >> 4) << 3) | r8;
        role = t & 15;
    } else {
        const int r8 = blockIdx.x & 7, t = blockIdx.x >> 3;   // t: 0..15
        bh = ((t >> 3) << 3) | r8;
        role = t & 7;
    }

    __shared__ int list[UU];
    __shared__ unsigned bmap[64];

    if (tid < 64) bmap[tid] = 0u;
    __syncthreads();
    if (tid < 64) {
        // wave-0 deterministic top-40 recompute (identical code+input across blocks)
        const int lane = tid;
        float vals[32];
        #pragma unroll
        for (int r = 0; r < 32; ++r) vals[r] = M[(long)bh * LL + r * 64 + lane];
        for (int it = 0; it < UU; ++it) {
            float lm = vals[0];
            #pragma unroll
            for (int r = 1; r < 32; ++r) lm = fmaxf(lm, vals[r]);
            float wm = lm;
            #pragma unroll
            for (int s = 1; s < 64; s <<= 1) wm = fmaxf(wm, __shfl_xor(wm, s, 64));
            unsigned long long mask = __ballot(lm == wm);
            int first = (int)__ffsll(mask) - 1;
            if (lane == first) {
                #pragma unroll
                for (int r = 0; r < 32; ++r) {
                    if (vals[r] == wm) { list[it] = r * 64 + lane; vals[r] = -INFINITY; break; }
                }
            }
        }
    }
    __syncthreads();
    if (tid < UU) atomicOr(&bmap[list[tid] >> 5], 1u << (list[tid] & 31));
    __syncthreads();

    if (isCum) {
        // ---- cumsum emit, skipping selected rows (scatter owns them) ----
        const int d = tid & 63, sc_ = tid >> 6;
        const int chunk = role * 4 + sc_;
        float carry = 0.f;
        for (int c = 0; c < chunk; ++c) carry += sums[((long)bh * 64 + c) * DK + d];
        const float* vb = v + ((long)bh * LL + chunk * 32) * DK + d;
        float* cb = ctx + ((long)bh * LL + chunk * 32) * DK + d;
        float run = carry;
        #pragma unroll
        for (int r = 0; r < 32; ++r) {
            run += vb[r * DK];
            const int l = chunk * 32 + r;
            if (!((bmap[l >> 5] >> (l & 31)) & 1u)) cb[r * DK] = run;
        }
        return;
    }

    // ---- scores role: 5 selected rows ----
    const int g = role;
    const int lane = tid & 63, wave = tid >> 6;
    __shared__ float qs[5][DK];
    __shared__ float sc[5][LL];          // 40 KB
    __shared__ float red[5][4];
    __shared__ float red2[4][5][DK];     // 5 KB

    if (tid < 80) {
        int u = tid >> 4, c4 = (tid & 15) * 4;
        *(float4*)&qs[u][c4] = *(const float4*)&q[((long)bh * LL + list[g * 5 + u]) * DK + c4];
    }
    __syncthreads();

    const float* kb = k + (long)bh * LL * DK;
    float a[8][5] = {};
    #pragma unroll
    for (int c = 0; c < DK; c += 4) {
        float4 qv[5];
        #pragma unroll
        for (int u = 0; u < 5; ++u) qv[u] = *(const float4*)&qs[u][c];
        #pragma unroll
        for (int r = 0; r < 8; ++r) {
            float4 kv = *(const float4*)&kb[(long)(tid + r * 256) * DK + c];
            #pragma unroll
            for (int u = 0; u < 5; ++u)
                a[r][u] += qv[u].x * kv.x + qv[u].y * kv.y + qv[u].z * kv.z + qv[u].w * kv.w;
        }
    }
    const float scale = 0.125f;
    #pragma unroll
    for (int r = 0; r < 8; ++r)
        #pragma unroll
        for (int u = 0; u < 5; ++u)
            sc[u][tid + r * 256] = a[r][u] * scale;
    __syncthreads();

    float xv[5][8];
    #pragma unroll
    for (int u = 0; u < 5; ++u) {
        float4 t0 = *(const float4*)&sc[u][tid * 8];
        float4 t1 = *(const float4*)&sc[u][tid * 8 + 4];
        xv[u][0] = t0.x; xv[u][1] = t0.y; xv[u][2] = t0.z; xv[u][3] = t0.w;
        xv[u][4] = t1.x; xv[u][5] = t1.y; xv[u][6] = t1.z; xv[u][7] = t1.w;
    }
    float mloc[5];
    #pragma unroll
    for (int u = 0; u < 5; ++u) {
        float m = xv[u][0];
        #pragma unroll
        for (int i = 1; i < 8; ++i) m = fmaxf(m, xv[u][i]);
        #pragma unroll
        for (int s = 1; s < 64; s <<= 1) m = fmaxf(m, __shfl_xor(m, s, 64));
        if (lane == 0) red[u][wave] = m;
        mloc[u] = m;
    }
    __syncthreads();
    #pragma unroll
    for (int u = 0; u < 5; ++u)
        mloc[u] = fmaxf(fmaxf(red[u][0], red[u][1]), fmaxf(red[u][2], red[u][3]));
    __syncthreads();
    #pragma unroll
    for (int u = 0; u < 5; ++u) {
        float s = 0.f;
        #pragma unroll
        for (int i = 0; i < 8; ++i) { xv[u][i] = expf(xv[u][i] - mloc[u]); s += xv[u][i]; }
        #pragma unroll
        for (int st = 1; st < 64; st <<= 1) s += __shfl_xor(s, st, 64);
        if (lane == 0) red[u][wave] = s;
    }
    __syncthreads();
    #pragma unroll
    for (int u = 0; u < 5; ++u) {
        float inv = 1.0f / (red[u][0] + red[u][1] + red[u][2] + red[u][3]);
        float* row = attns + ((long)bh * LL + list[g * 5 + u]) * LL;
        float4 o0, o1;
        o0.x = xv[u][0] * inv; o0.y = xv[u][1] * inv; o0.z = xv[u][2] * inv; o0.w = xv[u][3] * inv;
        o1.x = xv[u][4] * inv; o1.y = xv[u][5] * inv; o1.z = xv[u][6] * inv; o1.w = xv[u][7] * inv;
        *(float4*)&row[tid * 8] = o0;
        *(float4*)&row[tid * 8 + 4] = o1;
        *(float4*)&sc[u][tid * 8] = o0;       // normalized probs back to LDS for upd
        *(float4*)&sc[u][tid * 8 + 4] = o1;
    }
    __syncthreads();

    const int d = tid & 63, part = tid >> 6;
    const float* vb = v + (long)bh * LL * DK + d;
    float ua[5] = {};
    for (int l0 = part * 512; l0 < part * 512 + 512; l0 += 4) {
        float vv0 = vb[(long)(l0 + 0) * DK];
        float vv1 = vb[(long)(l0 + 1) * DK];
        float vv2 = vb[(long)(l0 + 2) * DK];
        float vv3 = vb[(long)(l0 + 3) * DK];
        #pragma unroll
        for (int u = 0; u < 5; ++u) {
            float4 pv = *(const float4*)&sc[u][l0];
            ua[u] += pv.x * vv0 + pv.y * vv1 + pv.z * vv2 + pv.w * vv3;
        }
    }
    #pragma unroll
    for (int u = 0; u < 5; ++u) red2[part][u][d] = ua[u];
    __syncthreads();
    if (part == 0) {
        #pragma unroll
        for (int u = 0; u < 5; ++u) {
            float s = red2[0][u][d] + red2[1][u][d] + red2[2][u][d] + red2[3][u][d];
            ctx[((long)bh * LL + list[g * 5 + u]) * DK + d] = s;
        }
    }
}

extern "C" void kernel_launch(void* const* d_in, const int* in_sizes, int n_in,
                              void* d_out, int out_size, void* d_ws, size_t ws_size,
                              hipStream_t stream) {
    const float* x  = (const float*)d_in[0];
    const float* Wq = (const float*)d_in[1];
    const float* bq = (const float*)d_in[2];
    const float* Wk = (const float*)d_in[3];
    const float* bk = (const float*)d_in[4];
    const float* Wv = (const float*)d_in[5];
    const float* bv = (const float*)d_in[6];
    const int* idxs = (const int*)d_in[7];

    float* ctx   = (float*)d_out;                            // B*H*L*DK (8 MB)
    float* attns = (float*)d_out + (long)BB * HH * LL * DK;  // B*H*L*L (268 MB)

    char* w = (char*)d_ws;
    float* q    = (float*)w; w += (size_t)BB * HH * LL * DK * 4;
    float* k    = (float*)w; w += (size_t)BB * HH * LL * DK * 4;
    float* v    = (float*)w; w += (size_t)BB * HH * LL * DK * 4;
    float* M    = (float*)w; w += (size_t)BB * HH * LL * 4;
    float* sums = (float*)w; w += (size_t)BH * 64 * DK * 4;
    ushort* Bh  = (ushort*)w; w += (size_t)3 * DD * DD * 2;
    ushort* Bl  = (ushort*)w; w += (size_t)3 * DD * DD * 2;

    // Ah/Al live in the ctx output region (consumed by K1; ctx written in K4)
    ushort* Ah = (ushort*)ctx;                  // 4 MB
    ushort* Al = Ah + (size_t)4096 * DD;        // 4 MB

    // K0: split-bf16 packing
    pack_split<<<1408, 256, 0, stream>>>(x, Wq, Wk, Wv, Ah, Al, Bh, Bl);

    // K1: MFMA projections (384 blocks) || fill attns (2048 blocks)
    k1_proj_fill<<<384 + 2048, 256, 0, stream>>>(Ah, Al, Bh, Bl, bq, bk, bv, q, k, v, attns);

    // K2: sampled QK^T 4-way split (512, XCD-swizzled) || cumsum chunk sums (256, swizzled)
    k2_qk_cumsum1<<<512 + 256, 256, 0, stream>>>(q, k, v, idxs, M, sums);

    // K4: topk-recompute + scores/softmax/upd/scatter (128) || cumsum emit (256), XCD-swizzled
    k4_all<<<128 + 256, 256, 0, stream>>>(q, k, v, M, sums, attns, ctx);
}